// Round 1
// baseline (1240.648 us; speedup 1.0000x reference)
//
#include <hip/hip_runtime.h>
#include <math.h>

// Problem constants (from reference setup_inputs)
constexpr int Bn = 16;
constexpr int Cn = 256;
constexpr int Ln = 16384;
constexpr int G  = 16;    // Cn / GROUP
constexpr int D  = 16;    // GROUP
constexpr int M_SAMP = Bn * Ln;            // samples per group = 262144
constexpr float EPSV = 1e-3f;

constexpr int BDIM = 256;
constexpr int NB1  = 64;   // blocks per group, stats pass
constexpr int NB3  = 64;   // blocks per group, apply pass
constexpr int NPAIR = D * (D + 1) / 2;     // 136 unique covariance entries
constexpr int NQ    = NPAIR + D;           // 152 reduced quantities per block
constexpr int NS_ITERS = 12;               // Newton-Schulz iterations

// ---------------------------------------------------------------------------
// Pass 1: per-(group, block) partial sums: s1[j] = sum x_j, s2[j][k] = sum x_j x_k
// ---------------------------------------------------------------------------
__global__ __launch_bounds__(BDIM, 2) void k_stats(const float* __restrict__ X,
                                                   float* __restrict__ partials) {
  const int g   = blockIdx.y;
  const int blk = blockIdx.x;
  const int tid = threadIdx.x;
  const float* __restrict__ Xg = X + (size_t)g * D * Ln;

  float acc[NPAIR];
  float s1[D];
#pragma unroll
  for (int i = 0; i < NPAIR; ++i) acc[i] = 0.f;
#pragma unroll
  for (int i = 0; i < D; ++i) s1[i] = 0.f;

  const int stride = NB1 * BDIM * 2;
  for (int s0 = (blk * BDIM + tid) * 2; s0 < M_SAMP; s0 += stride) {
    const int b = s0 >> 14;            // Ln = 16384
    const int l = s0 & (Ln - 1);
    const float* p = Xg + (size_t)b * (Cn * Ln) + l;
    float2 x[D];
#pragma unroll
    for (int j = 0; j < D; ++j) x[j] = *(const float2*)(p + (size_t)j * Ln);
#pragma unroll
    for (int j = 0; j < D; ++j) {
      s1[j] += x[j].x + x[j].y;
#pragma unroll
      for (int k = 0; k <= j; ++k) {
        float a = acc[j * (j + 1) / 2 + k];
        a = fmaf(x[j].x, x[k].x, a);
        a = fmaf(x[j].y, x[k].y, a);
        acc[j * (j + 1) / 2 + k] = a;
      }
    }
  }

  // block reduction: wave shfl tree, then cross-wave via LDS
  __shared__ float red[4 * NQ];
  const int wave = tid >> 6, lane = tid & 63;
#pragma unroll
  for (int q = 0; q < NPAIR; ++q) {
    float v = acc[q];
#pragma unroll
    for (int off = 32; off; off >>= 1) v += __shfl_xor(v, off);
    if (lane == 0) red[wave * NQ + q] = v;
  }
#pragma unroll
  for (int j = 0; j < D; ++j) {
    float v = s1[j];
#pragma unroll
    for (int off = 32; off; off >>= 1) v += __shfl_xor(v, off);
    if (lane == 0) red[wave * NQ + NPAIR + j] = v;
  }
  __syncthreads();
  if (tid < NQ) {
    float v = red[tid] + red[NQ + tid] + red[2 * NQ + tid] + red[3 * NQ + tid];
    partials[(size_t)(g * NB1 + blk) * NQ + tid] = v;
  }
}

// ---------------------------------------------------------------------------
// Pass 2: reduce partials -> sigma (16x16/group), Newton-Schulz inverse sqrt,
// fold weight/bias into per-group apply matrix M and offset vector.
// One block per group, 256 threads = one thread per matrix element.
// ---------------------------------------------------------------------------
__global__ __launch_bounds__(256, 1) void k_solve(const float* __restrict__ partials,
                                                  const float* __restrict__ weight,
                                                  const float* __restrict__ bias,
                                                  float* __restrict__ Mbuf,
                                                  float* __restrict__ offbuf) {
  const int g = blockIdx.x;
  const int tid = threadIdx.x;
  __shared__ float S2s[NPAIR];
  __shared__ float means[D];
  __shared__ float Ybuf[D * D], Zbuf[D * D], Tbuf[D * D];
  __shared__ float red4[4];
  __shared__ float scale_s;

  // reduce the NB1 per-block partials for this group
  if (tid < NQ) {
    float v = 0.f;
    const float* p = partials + (size_t)g * NB1 * NQ + tid;
    for (int i = 0; i < NB1; ++i) v += p[(size_t)i * NQ];
    if (tid < NPAIR) S2s[tid] = v;
    else            means[tid - NPAIR] = v * (1.0f / M_SAMP);
  }
  __syncthreads();

  const int r = tid >> 4, c = tid & 15;
  // sigma[r][c] = S2/m - mean_r*mean_c + eps*(r==c)
  const int jj = (r > c) ? r : c;
  const int kk = (r > c) ? c : r;
  float sig = S2s[jj * (jj + 1) / 2 + kk] * (1.0f / M_SAMP) - means[r] * means[c];
  if (r == c) sig += EPSV;

  // Frobenius norm of sigma (block reduction of sig^2)
  float v2 = sig * sig;
#pragma unroll
  for (int off = 32; off; off >>= 1) v2 += __shfl_xor(v2, off);
  if ((tid & 63) == 0) red4[tid >> 6] = v2;
  __syncthreads();
  if (tid == 0) scale_s = 1.0f / sqrtf(red4[0] + red4[1] + red4[2] + red4[3]);
  __syncthreads();
  const float inv_f = scale_s;   // 1/||sigma||_F

  // Newton-Schulz: Y0 = sigma/f, Z0 = I;  Y->A^{1/2}, Z->A^{-1/2}
  Ybuf[tid] = sig * inv_f;
  Zbuf[tid] = (r == c) ? 1.0f : 0.0f;
  __syncthreads();

  for (int it = 0; it < NS_ITERS; ++it) {
    float t = 0.f;
#pragma unroll
    for (int k = 0; k < D; ++k) t = fmaf(Zbuf[r * D + k], Ybuf[k * D + c], t);
    t = ((r == c) ? 1.5f : 0.0f) - 0.5f * t;
    Tbuf[tid] = t;
    __syncthreads();
    float ny = 0.f, nz = 0.f;
#pragma unroll
    for (int k = 0; k < D; ++k) {
      ny = fmaf(Ybuf[r * D + k], Tbuf[k * D + c], ny);
      nz = fmaf(Tbuf[r * D + k], Zbuf[k * D + c], nz);
    }
    __syncthreads();
    Ybuf[tid] = ny;
    Zbuf[tid] = nz;
    __syncthreads();
  }

  // sigma^{-1/2} = Z * f^{-1/2}
  const float wms = sqrtf(inv_f);
  const int ch = g * D + r;
  const float w = weight[ch];
  Mbuf[(size_t)g * D * D + tid] = w * Zbuf[tid] * wms;
  if (tid < D) {
    float dot = 0.f;
#pragma unroll
    for (int e = 0; e < D; ++e) dot = fmaf(Zbuf[tid * D + e], means[e], dot);
    offbuf[g * D + tid] = bias[g * D + tid] - weight[g * D + tid] * wms * dot;
  }
}

// ---------------------------------------------------------------------------
// Pass 3: out[b, g*16+j, l] = sum_e M[j][e] * X[b, g*16+e, l] + off[j]
// ---------------------------------------------------------------------------
__global__ __launch_bounds__(BDIM, 4) void k_apply(const float* __restrict__ X,
                                                   const float* __restrict__ Mbuf,
                                                   const float* __restrict__ offbuf,
                                                   float* __restrict__ out) {
  const int g = blockIdx.y;
  const int tid = threadIdx.x;
  __shared__ float Ms[D * D];
  __shared__ float offs[D];
  if (tid < D * D) Ms[tid] = Mbuf[(size_t)g * D * D + tid];
  if (tid < D) offs[tid] = offbuf[g * D + tid];
  __syncthreads();

  float offr[D];
#pragma unroll
  for (int j = 0; j < D; ++j) offr[j] = offs[j];

  const size_t gbase = (size_t)g * D * Ln;
  const int stride = NB3 * BDIM * 4;
  for (int s0 = (blockIdx.x * BDIM + tid) * 4; s0 < M_SAMP; s0 += stride) {
    const int b = s0 >> 14;
    const int l = s0 & (Ln - 1);
    const float* p = X + (size_t)b * (Cn * Ln) + gbase + l;
    float4 acc[D];
#pragma unroll
    for (int j = 0; j < D; ++j)
      acc[j] = make_float4(offr[j], offr[j], offr[j], offr[j]);
#pragma unroll
    for (int e = 0; e < D; ++e) {
      const float4 xe = *(const float4*)(p + (size_t)e * Ln);
#pragma unroll
      for (int j = 0; j < D; ++j) {
        const float mje = Ms[j * D + e];
        acc[j].x = fmaf(mje, xe.x, acc[j].x);
        acc[j].y = fmaf(mje, xe.y, acc[j].y);
        acc[j].z = fmaf(mje, xe.z, acc[j].z);
        acc[j].w = fmaf(mje, xe.w, acc[j].w);
      }
    }
    float* q = out + (size_t)b * (Cn * Ln) + gbase + l;
#pragma unroll
    for (int j = 0; j < D; ++j)
      *(float4*)(q + (size_t)j * Ln) = acc[j];
  }
}

// ---------------------------------------------------------------------------
extern "C" void kernel_launch(void* const* d_in, const int* in_sizes, int n_in,
                              void* d_out, int out_size, void* d_ws, size_t ws_size,
                              hipStream_t stream) {
  const float* X      = (const float*)d_in[0];
  const float* weight = (const float*)d_in[1];
  const float* bias   = (const float*)d_in[2];
  float* out = (float*)d_out;

  float* partials = (float*)d_ws;                                  // G*NB1*NQ
  float* Mbuf     = partials + (size_t)G * NB1 * NQ;               // G*D*D
  float* offbuf   = Mbuf + (size_t)G * D * D;                      // G*D

  dim3 g1(NB1, G);
  k_stats<<<g1, dim3(BDIM), 0, stream>>>(X, partials);
  k_solve<<<dim3(G), dim3(256), 0, stream>>>(partials, weight, bias, Mbuf, offbuf);
  dim3 g3(NB3, G);
  k_apply<<<g3, dim3(BDIM), 0, stream>>>(X, Mbuf, offbuf, out);
}

// Round 2
// 716.036 us; speedup vs baseline: 1.7327x; 1.7327x over previous
//
#include <hip/hip_runtime.h>
#include <math.h>

// Problem constants (from reference setup_inputs)
constexpr int Bn = 16;
constexpr int Cn = 256;
constexpr int Ln = 16384;
constexpr int G  = 16;    // Cn / GROUP
constexpr int D  = 16;    // GROUP
constexpr int M_SAMP = Bn * Ln;            // samples per group = 262144
constexpr float EPSV = 1e-3f;

constexpr int BDIM = 256;
constexpr int NB1  = 64;   // blocks per group, stats pass (4096 samples/block)
constexpr int NB3  = 64;   // blocks per group, apply pass
constexpr int NPAIR = D * (D + 1) / 2;     // 136 unique covariance entries
constexpr int NQ    = NPAIR + D;           // 152 reduced quantities per block
constexpr int NS_ITERS = 12;               // Newton-Schulz iterations

__device__ __forceinline__ float sgpr_bcast(float v) {
  return __uint_as_float((unsigned)__builtin_amdgcn_readfirstlane((int)__float_as_uint(v)));
}

// ---------------------------------------------------------------------------
// Pass 1: per-(group, block) partial sums. The 136-pair triangle is split
// across the 4 waves by ROW SETS so all channel indices are compile-time
// (register arrays never runtime-indexed -> no scratch).
//   wave0: rows {0,1,14,15}  wave1: {2,3,12,13}
//   wave2: rows {4,5,10,11}  wave3: {6,7,8,9}      (34 pairs each)
// Each wave also sums its 4 rows' channels (mean). All 4 waves read the same
// samples; L1 serves the 3 re-reads.
// ---------------------------------------------------------------------------
template<int J, int BASE>
__device__ __forceinline__ void row_fma2(const float2* x, float* acc) {
#pragma unroll
  for (int k = 0; k <= J; ++k) {
    float a = acc[BASE + k];
    a = fmaf(x[J].x, x[k].x, a);
    a = fmaf(x[J].y, x[k].y, a);
    acc[BASE + k] = a;
  }
}

template<int J, int BASE>
__device__ __forceinline__ void row_store(const float* acc, float* dst) {
#pragma unroll
  for (int k = 0; k <= J; ++k) dst[J * (J + 1) / 2 + k] = acc[BASE + k];
}

template<int JA, int JB, int JC, int JD>
__device__ __forceinline__ void stats_wave(const float* __restrict__ Xg, int blk, int lane,
                                           float* __restrict__ pblk) {
  constexpr int BA = 0, BB = JA + 1, BC = BB + JB + 1, BD = BC + JC + 1;
  constexpr int NACC = BD + JD + 1;     // = 34
  float acc[NACC];
  float s1a = 0.f, s1b = 0.f, s1c = 0.f, s1d = 0.f;
#pragma unroll
  for (int i = 0; i < NACC; ++i) acc[i] = 0.f;

  const int b  = blk >> 2;              // 4096-sample chunks: 4 per batch-row
  const int l0 = (blk & 3) * 4096;
  const float* base = Xg + (size_t)b * (Cn * Ln) + l0 + lane * 2;

  for (int it = 0; it < 32; ++it) {
    const float* p = base + it * 128;
    float2 x[16];
#pragma unroll
    for (int j = 0; j < 16; ++j) x[j] = *(const float2*)(p + (size_t)j * Ln);
    row_fma2<JA, BA>(x, acc);
    row_fma2<JB, BB>(x, acc);
    row_fma2<JC, BC>(x, acc);
    row_fma2<JD, BD>(x, acc);
    s1a += x[JA].x + x[JA].y;
    s1b += x[JB].x + x[JB].y;
    s1c += x[JC].x + x[JC].y;
    s1d += x[JD].x + x[JD].y;
  }

#pragma unroll
  for (int i = 0; i < NACC; ++i) {
    float v = acc[i];
#pragma unroll
    for (int off = 32; off; off >>= 1) v += __shfl_xor(v, off);
    acc[i] = v;
  }
#pragma unroll
  for (int off = 32; off; off >>= 1) {
    s1a += __shfl_xor(s1a, off);
    s1b += __shfl_xor(s1b, off);
    s1c += __shfl_xor(s1c, off);
    s1d += __shfl_xor(s1d, off);
  }

  if (lane == 0) {
    row_store<JA, BA>(acc, pblk);
    row_store<JB, BB>(acc, pblk);
    row_store<JC, BC>(acc, pblk);
    row_store<JD, BD>(acc, pblk);
    pblk[NPAIR + JA] = s1a;
    pblk[NPAIR + JB] = s1b;
    pblk[NPAIR + JC] = s1c;
    pblk[NPAIR + JD] = s1d;
  }
}

__global__ __launch_bounds__(BDIM, 4) void k_stats(const float* __restrict__ X,
                                                   float* __restrict__ partials) {
  const int g   = blockIdx.y;
  const int blk = blockIdx.x;
  const int tid  = threadIdx.x;
  const int wave = tid >> 6, lane = tid & 63;
  const float* Xg = X + (size_t)g * D * Ln;
  float* pblk = partials + (size_t)(g * NB1 + blk) * NQ;
  switch (wave) {
    case 0: stats_wave<0, 1, 14, 15>(Xg, blk, lane, pblk); break;
    case 1: stats_wave<2, 3, 12, 13>(Xg, blk, lane, pblk); break;
    case 2: stats_wave<4, 5, 10, 11>(Xg, blk, lane, pblk); break;
    default: stats_wave<6, 7, 8, 9>(Xg, blk, lane, pblk); break;
  }
}

// ---------------------------------------------------------------------------
// Pass 2: reduce partials -> sigma, Newton-Schulz inverse sqrt, fold
// weight/bias into per-group apply matrix M and offset vector. (Unchanged.)
// ---------------------------------------------------------------------------
__global__ __launch_bounds__(256, 1) void k_solve(const float* __restrict__ partials,
                                                  const float* __restrict__ weight,
                                                  const float* __restrict__ bias,
                                                  float* __restrict__ Mbuf,
                                                  float* __restrict__ offbuf) {
  const int g = blockIdx.x;
  const int tid = threadIdx.x;
  __shared__ float S2s[NPAIR];
  __shared__ float means[D];
  __shared__ float Ybuf[D * D], Zbuf[D * D], Tbuf[D * D];
  __shared__ float red4[4];
  __shared__ float scale_s;

  if (tid < NQ) {
    float v = 0.f;
    const float* p = partials + (size_t)g * NB1 * NQ + tid;
    for (int i = 0; i < NB1; ++i) v += p[(size_t)i * NQ];
    if (tid < NPAIR) S2s[tid] = v;
    else            means[tid - NPAIR] = v * (1.0f / M_SAMP);
  }
  __syncthreads();

  const int r = tid >> 4, c = tid & 15;
  const int jj = (r > c) ? r : c;
  const int kk = (r > c) ? c : r;
  float sig = S2s[jj * (jj + 1) / 2 + kk] * (1.0f / M_SAMP) - means[r] * means[c];
  if (r == c) sig += EPSV;

  float v2 = sig * sig;
#pragma unroll
  for (int off = 32; off; off >>= 1) v2 += __shfl_xor(v2, off);
  if ((tid & 63) == 0) red4[tid >> 6] = v2;
  __syncthreads();
  if (tid == 0) scale_s = 1.0f / sqrtf(red4[0] + red4[1] + red4[2] + red4[3]);
  __syncthreads();
  const float inv_f = scale_s;

  Ybuf[tid] = sig * inv_f;
  Zbuf[tid] = (r == c) ? 1.0f : 0.0f;
  __syncthreads();

  for (int it = 0; it < NS_ITERS; ++it) {
    float t = 0.f;
#pragma unroll
    for (int k = 0; k < D; ++k) t = fmaf(Zbuf[r * D + k], Ybuf[k * D + c], t);
    t = ((r == c) ? 1.5f : 0.0f) - 0.5f * t;
    Tbuf[tid] = t;
    __syncthreads();
    float ny = 0.f, nz = 0.f;
#pragma unroll
    for (int k = 0; k < D; ++k) {
      ny = fmaf(Ybuf[r * D + k], Tbuf[k * D + c], ny);
      nz = fmaf(Tbuf[r * D + k], Zbuf[k * D + c], nz);
    }
    __syncthreads();
    Ybuf[tid] = ny;
    Zbuf[tid] = nz;
    __syncthreads();
  }

  const float wms = sqrtf(inv_f);
  const int ch = g * D + r;
  const float w = weight[ch];
  Mbuf[(size_t)g * D * D + tid] = w * Zbuf[tid] * wms;
  if (tid < D) {
    float dot = 0.f;
#pragma unroll
    for (int e = 0; e < D; ++e) dot = fmaf(Zbuf[tid * D + e], means[e], dot);
    offbuf[g * D + tid] = bias[g * D + tid] - weight[g * D + tid] * wms * dot;
  }
}

// ---------------------------------------------------------------------------
// Pass 3: out[b, g*16+j, l] = sum_e M[j][e] * X[b, g*16+e, l] + off[j]
// Wave w of each block computes output channels 4w..4w+3 for the block's
// whole 4096-sample chunk. M rows + offsets live in SGPRs (readfirstlane),
// inner loop is v_fmac_f32 vacc, s_m, v_x — no LDS, no spills.
// ---------------------------------------------------------------------------
__global__ __launch_bounds__(BDIM, 4) void k_apply(const float* __restrict__ X,
                                                   const float* __restrict__ Mbuf,
                                                   const float* __restrict__ offbuf,
                                                   float* __restrict__ out) {
  const int g   = blockIdx.y;
  const int blk = blockIdx.x;
  const int tid = threadIdx.x;
  const int w = tid >> 6, lane = tid & 63;

  float m[4][16], off[4];
  const float* Mg = Mbuf + (size_t)g * D * D + (size_t)(w * 4) * D;
#pragma unroll
  for (int a = 0; a < 4; ++a) {
#pragma unroll
    for (int e = 0; e < 16; ++e) m[a][e] = sgpr_bcast(Mg[a * D + e]);
    off[a] = sgpr_bcast(offbuf[g * D + w * 4 + a]);
  }

  const int b  = blk >> 2;
  const int l0 = (blk & 3) * 4096;
  const size_t cbase = (size_t)b * (Cn * Ln) + (size_t)g * D * Ln + l0 + lane * 4;
  const float* __restrict__ px = X + cbase;
  float* __restrict__ po = out + cbase + (size_t)(w * 4) * Ln;

  for (int it = 0; it < 16; ++it) {
    const float* p = px + it * 256;
    float4 x[16];
#pragma unroll
    for (int e = 0; e < 16; ++e) x[e] = *(const float4*)(p + (size_t)e * Ln);
    float4 acc[4];
#pragma unroll
    for (int a = 0; a < 4; ++a) acc[a] = make_float4(off[a], off[a], off[a], off[a]);
#pragma unroll
    for (int e = 0; e < 16; ++e) {
#pragma unroll
      for (int a = 0; a < 4; ++a) {
        acc[a].x = fmaf(m[a][e], x[e].x, acc[a].x);
        acc[a].y = fmaf(m[a][e], x[e].y, acc[a].y);
        acc[a].z = fmaf(m[a][e], x[e].z, acc[a].z);
        acc[a].w = fmaf(m[a][e], x[e].w, acc[a].w);
      }
    }
    float* q = po + it * 256;
#pragma unroll
    for (int a = 0; a < 4; ++a) *(float4*)(q + (size_t)a * Ln) = acc[a];
  }
}

// ---------------------------------------------------------------------------
extern "C" void kernel_launch(void* const* d_in, const int* in_sizes, int n_in,
                              void* d_out, int out_size, void* d_ws, size_t ws_size,
                              hipStream_t stream) {
  const float* X      = (const float*)d_in[0];
  const float* weight = (const float*)d_in[1];
  const float* bias   = (const float*)d_in[2];
  float* out = (float*)d_out;

  float* partials = (float*)d_ws;                                  // G*NB1*NQ
  float* Mbuf     = partials + (size_t)G * NB1 * NQ;               // G*D*D
  float* offbuf   = Mbuf + (size_t)G * D * D;                      // G*D

  dim3 g1(NB1, G);
  k_stats<<<g1, dim3(BDIM), 0, stream>>>(X, partials);
  k_solve<<<dim3(G), dim3(256), 0, stream>>>(partials, weight, bias, Mbuf, offbuf);
  dim3 g3(NB3, G);
  k_apply<<<g3, dim3(BDIM), 0, stream>>>(X, Mbuf, offbuf, out);
}